// Round 3
// baseline (321.733 us; speedup 1.0000x reference)
//
#include <hip/hip_runtime.h>
#include <math.h>

#define T_DIM 2048
#define N_DIM 64
#define E_DIM 1024
#define A_DIM 256

typedef __bf16 bf16x8 __attribute__((ext_vector_type(8)));
typedef float f32x4 __attribute__((ext_vector_type(4)));

__device__ __forceinline__ float tanh_fast(float x) {
    float xc = fminf(fmaxf(x, -15.f), 15.f);
    float e = __expf(2.f * xc);
    return (e - 1.f) / (e + 1.f);
}

// ---- W_e fp32 [A,E] -> bf16, permuted: unit (kt,g,a) = W_e[a][kt*32+g*8..+8]
// at offset ((kt*4+g)*256+a)*8   (kt in 0..31, g in 0..3, a in 0..255)
__global__ __launch_bounds__(256) void convert_W(const float* __restrict__ W_e,
                                                 __bf16* __restrict__ Wp) {
    const int uid = blockIdx.x * 256 + threadIdx.x;  // 32768 units
    const int a = uid >> 7;
    const int c = uid & 127;  // c = kt*4+g
    const float4* src = (const float4*)(W_e + (size_t)a * E_DIM + c * 8);
    float4 x0 = src[0], x1 = src[1];
    bf16x8 o;
    o[0] = (__bf16)x0.x; o[1] = (__bf16)x0.y; o[2] = (__bf16)x0.z; o[3] = (__bf16)x0.w;
    o[4] = (__bf16)x1.x; o[5] = (__bf16)x1.y; o[6] = (__bf16)x1.z; o[7] = (__bf16)x1.w;
    *(bf16x8*)(Wp + ((size_t)c * 256 + a) * 8) = o;
}

// ---------------- d_proj[n][a] = dot(dec_h[n,:], W_d[a,:]) ----------------
__global__ __launch_bounds__(256) void dproj_kernel(
    const float* __restrict__ dec_h, const float* __restrict__ W_d,
    float* __restrict__ d_proj) {
    __shared__ float dec[E_DIM];
    const int n = blockIdx.x;
    const int tid = threadIdx.x;
    reinterpret_cast<float4*>(dec)[tid] =
        reinterpret_cast<const float4*>(dec_h + (size_t)n * E_DIM)[tid];
    __syncthreads();
    const float* w = W_d + (size_t)tid * E_DIM;
    float acc = 0.f;
#pragma unroll 4
    for (int e = 0; e < E_DIM; e += 4) {
        float4 wv = *reinterpret_cast<const float4*>(w + e);
        acc = fmaf(wv.x, dec[e], acc);
        acc = fmaf(wv.y, dec[e + 1], acc);
        acc = fmaf(wv.z, dec[e + 2], acc);
        acc = fmaf(wv.w, dec[e + 3], acc);
    }
    d_proj[n * A_DIM + tid] = acc;
}

// ---- fused scores: 64x256 tile, BK=32, 256 threads = 4 waves (1m x 4n),
// wave tile 64x64 = 4x4 frags of 16x16x32. acc=64 VGPR -> 3-4 blocks/CU.
__global__ __launch_bounds__(256, 4) void scores_mfma(
    const float* __restrict__ enc, const __bf16* __restrict__ Wp,
    const float* __restrict__ dproj, const float* __restrict__ v,
    float* __restrict__ scores) {
    __shared__ __bf16 Ab[2][2048];  // [g][row][8]: 4*64*8,  2 x 4 KB
    __shared__ __bf16 Bb[2][8192];  // [g][a][8] : 4*256*8,  2 x 16 KB

    const int tid = threadIdx.x;
    const int m0 = blockIdx.x * 64;
    const int wn = tid >> 6;  // wave = a-quadrant
    const int lane = tid & 63;
    const int lr = lane & 15, lg = lane >> 4;

    f32x4 acc[4][4];
#pragma unroll
    for (int i = 0; i < 4; ++i)
#pragma unroll
        for (int j = 0; j < 4; ++j) acc[i][j] = (f32x4){0.f, 0.f, 0.f, 0.f};

    const int arow = tid >> 2, ag = tid & 3;
    const float* encA = enc + (size_t)(m0 + arow) * E_DIM + ag * 8;
    const bf16x8* WpV = (const bf16x8*)Wp;

    // prologue: stage kt=0
    {
        float4 a0 = *(const float4*)encA;
        float4 a1 = *(const float4*)(encA + 4);
        bf16x8 b0 = WpV[tid], b1 = WpV[256 + tid], b2 = WpV[512 + tid],
               b3 = WpV[768 + tid];
        bf16x8 p;
        p[0] = (__bf16)a0.x; p[1] = (__bf16)a0.y; p[2] = (__bf16)a0.z; p[3] = (__bf16)a0.w;
        p[4] = (__bf16)a1.x; p[5] = (__bf16)a1.y; p[6] = (__bf16)a1.z; p[7] = (__bf16)a1.w;
        ((bf16x8*)Ab[0])[ag * 64 + arow] = p;
        bf16x8* Bn = (bf16x8*)Bb[0];
        Bn[tid] = b0; Bn[256 + tid] = b1; Bn[512 + tid] = b2; Bn[768 + tid] = b3;
    }
    __syncthreads();

    float4 aR0, aR1;
    bf16x8 bR0, bR1, bR2, bR3;
    for (int kt = 0; kt < 32; ++kt) {
        const int cur = kt & 1;
        if (kt < 31) {  // issue next-tile loads early (hide under MFMA)
            const float* pA = encA + (kt + 1) * 32;
            aR0 = *(const float4*)pA;
            aR1 = *(const float4*)(pA + 4);
            const bf16x8* pB = WpV + (size_t)(kt + 1) * 1024 + tid;
            bR0 = pB[0]; bR1 = pB[256]; bR2 = pB[512]; bR3 = pB[768];
        }
        const bf16x8* As = (const bf16x8*)Ab[cur];
        const bf16x8* Bs = (const bf16x8*)Bb[cur];
        bf16x8 bfr[4];
#pragma unroll
        for (int fn = 0; fn < 4; ++fn)
            bfr[fn] = Bs[lg * 256 + wn * 64 + fn * 16 + lr];
#pragma unroll
        for (int fm = 0; fm < 4; ++fm) {
            bf16x8 af = As[lg * 64 + fm * 16 + lr];
#pragma unroll
            for (int fn = 0; fn < 4; ++fn)
                acc[fm][fn] = __builtin_amdgcn_mfma_f32_16x16x32_bf16(
                    af, bfr[fn], acc[fm][fn], 0, 0, 0);
        }
        __syncthreads();  // reads of buf[cur] done
        if (kt < 31) {    // write-late into the other buffer
            bf16x8 p;
            p[0] = (__bf16)aR0.x; p[1] = (__bf16)aR0.y; p[2] = (__bf16)aR0.z; p[3] = (__bf16)aR0.w;
            p[4] = (__bf16)aR1.x; p[5] = (__bf16)aR1.y; p[6] = (__bf16)aR1.z; p[7] = (__bf16)aR1.w;
            ((bf16x8*)Ab[cur ^ 1])[ag * 64 + arow] = p;
            bf16x8* Bn = (bf16x8*)Bb[cur ^ 1];
            Bn[tid] = bR0; Bn[256 + tid] = bR1; Bn[512 + tid] = bR2;
            Bn[768 + tid] = bR3;
        }
        __syncthreads();
    }

    // ---- epilogue: tanh(e+d) dot v, reduce over a ----
    float vv[4];
#pragma unroll
    for (int fn = 0; fn < 4; ++fn) vv[fn] = v[wn * 64 + fn * 16 + lr];
    float* red = (float*)Ab[0];  // 256 floats, safe after final barrier
#pragma unroll
    for (int fm = 0; fm < 4; ++fm) {
#pragma unroll
        for (int reg = 0; reg < 4; ++reg) {
            const int r = fm * 16 + lg * 4 + reg;  // row in tile; n = r (m0%64==0)
            float p = 0.f;
#pragma unroll
            for (int fn = 0; fn < 4; ++fn) {
                const int a = wn * 64 + fn * 16 + lr;
                p = fmaf(vv[fn], tanh_fast(acc[fm][fn][reg] + dproj[r * A_DIM + a]), p);
            }
            p += __shfl_xor(p, 1);
            p += __shfl_xor(p, 2);
            p += __shfl_xor(p, 4);
            p += __shfl_xor(p, 8);
            if (lr == 0) red[wn * 64 + r] = p;
        }
    }
    __syncthreads();
    if (tid < 64)
        scores[m0 + tid] =
            red[tid] + red[64 + tid] + red[128 + tid] + red[192 + tid];
}

// ---------------- softmax over t per column n ----------------
__global__ __launch_bounds__(256) void softmax_kernel(
    const float* __restrict__ scores, float* __restrict__ alpha) {
    __shared__ float red[256];
    const int n = blockIdx.x;
    const int tid = threadIdx.x;
    float m = -3.4e38f;
    for (int t = tid; t < T_DIM; t += 256)
        m = fmaxf(m, scores[t * N_DIM + n]);
    red[tid] = m;
    __syncthreads();
    for (int s = 128; s; s >>= 1) {
        if (tid < s) red[tid] = fmaxf(red[tid], red[tid + s]);
        __syncthreads();
    }
    m = red[0];
    __syncthreads();
    float sum = 0.f;
    for (int t = tid; t < T_DIM; t += 256)
        sum += expf(scores[t * N_DIM + n] - m);
    red[tid] = sum;
    __syncthreads();
    for (int s = 128; s; s >>= 1) {
        if (tid < s) red[tid] += red[tid + s];
        __syncthreads();
    }
    const float inv = 1.f / red[0];
    for (int t = tid; t < T_DIM; t += 256)
        alpha[t * N_DIM + n] = expf(scores[t * N_DIM + n] - m) * inv;
}

// ---------------- ctx partials (reversed chunks -> L3-hot tail first) ------
__global__ __launch_bounds__(256) void ctx_partial_kernel(
    const float* __restrict__ enc, const float* __restrict__ alpha,
    float* __restrict__ out, int tlen, int nchunk) {
    __shared__ float als[512];
    const int n = blockIdx.x;
    const int tc = blockIdx.y;
    const int tid = threadIdx.x;
    const int t0 = (nchunk - 1 - tc) * tlen;  // high-t chunks first
    for (int i = tid; i < tlen; i += 256) als[i] = alpha[(t0 + i) * N_DIM + n];
    __syncthreads();
    float4 acc = {0.f, 0.f, 0.f, 0.f};
#pragma unroll 4
    for (int i = 0; i < tlen; ++i) {
        const float al = als[i];
        float4 ev = *reinterpret_cast<const float4*>(
            enc + (size_t)((t0 + i) * N_DIM + n) * E_DIM + tid * 4);
        acc.x = fmaf(al, ev.x, acc.x);
        acc.y = fmaf(al, ev.y, acc.y);
        acc.z = fmaf(al, ev.z, acc.z);
        acc.w = fmaf(al, ev.w, acc.w);
    }
    *reinterpret_cast<float4*>(out + ((size_t)tc * N_DIM + n) * E_DIM +
                               tid * 4) = acc;
}

__global__ __launch_bounds__(256) void ctx_reduce_kernel(
    const float* __restrict__ partial, float* __restrict__ ctx, int nchunk) {
    const int idx = blockIdx.x * 256 + threadIdx.x;
    float s = 0.f;
    for (int c = 0; c < nchunk; ++c) s += partial[(size_t)c * 65536 + idx];
    ctx[idx] = s;
}

extern "C" void kernel_launch(void* const* d_in, const int* in_sizes, int n_in,
                              void* d_out, int out_size, void* d_ws,
                              size_t ws_size, hipStream_t stream) {
    const float* enc = (const float*)d_in[0];    // [T,N,E]
    const float* dec_h = (const float*)d_in[1];  // [N,D]
    const float* W_e = (const float*)d_in[2];    // [A,E]
    const float* W_d = (const float*)d_in[3];    // [A,D]
    const float* v = (const float*)d_in[4];      // [1,A]

    float* out = (float*)d_out;
    float* ctx = out;            // 64*1024
    float* alpha = out + 65536;  // 2048*64

    float* ws = (float*)d_ws;
    float* d_proj = ws;                       // 16384 floats
    float* scores = ws + 16384;               // 131072 floats
    __bf16* Wp = (__bf16*)(ws + 147456);      // 262144 bf16 = 131072 floats
    float* partial = ws + 278528;             // nchunk*65536 floats

    convert_W<<<128, 256, 0, stream>>>(W_e, Wp);
    dproj_kernel<<<N_DIM, 256, 0, stream>>>(dec_h, W_d, d_proj);
    scores_mfma<<<(T_DIM * N_DIM) / 64, 256, 0, stream>>>(enc, Wp, d_proj, v,
                                                          scores);
    softmax_kernel<<<N_DIM, 256, 0, stream>>>(scores, alpha);

    const size_t need16 = (size_t)(278528 + 16 * 65536) * sizeof(float);
    if (ws_size >= need16) {
        dim3 g(N_DIM, 16);
        ctx_partial_kernel<<<g, 256, 0, stream>>>(enc, alpha, partial,
                                                  T_DIM / 16, 16);
        ctx_reduce_kernel<<<256, 256, 0, stream>>>(partial, ctx, 16);
    } else {
        dim3 g(N_DIM, 1);
        ctx_partial_kernel<<<g, 256, 0, stream>>>(enc, alpha, ctx, T_DIM, 1);
    }
}